// Round 15
// baseline (155.066 us; speedup 1.0000x reference)
//
#include <hip/hip_runtime.h>

#define B_ 1024
#define S_ 256
#define D_ 128
#define K_ 26
#define WIN 32   // hist ring slots (power of 2)

typedef float v2f __attribute__((ext_vector_type(2)));
#define EMAX(a, b) __builtin_elementwise_max((a), (b))

// 3-wave fused CRF: wave0 = consumer (minimal serial recurrence),
// wave1 = producer (emissions, r14-proven), wave2 = bp-helper (recomputes
// backpointers from the delta history ring, bit-identical operands).
__global__ __launch_bounds__(192, 3) void crf_pc3(
    const float* __restrict__ X, const float* __restrict__ W,
    const float* __restrict__ Tr, int* __restrict__ out)
{
  __shared__ __align__(16) float e_lds[S_ * K_];    // 26624 B (aliased in phase 3)
  __shared__ __align__(16) float hist[WIN * 28];    //  3584 B delta history ring
  __shared__ unsigned char bp[K_][260];             //  6760 B
  __shared__ __align__(16) float ring[2][D_];       //  1024 B producer dbuf
  __shared__ int prog[8];                           //    32 B (~38.0 KB total)

  const int tid  = threadIdx.x;
  const int lane = tid & 63;
  const int wv   = tid >> 6;                        // 0 consumer, 1 producer, 2 helper
  const int b    = blockIdx.x;

  if (tid == 0) { prog[0] = 0; prog[1] = -1; prog[2] = 0; }
  __syncthreads();                                  // only all-wave barrier

  if (wv == 1) {
    // ---------------- producer wave: emissions (r14-proven bits) ----------------
    const int j  = lane & 31;
    const int h  = lane >> 5;
    const int jc = (j < K_) ? j : (K_ - 1);
    float w[64];
    {
      const float4* wp = reinterpret_cast<const float4*>(W + jc * D_ + h * 64);
#pragma unroll
      for (int q = 0; q < 16; ++q) {
        float4 v4 = wp[q];
        w[4*q+0] = v4.x; w[4*q+1] = v4.y; w[4*q+2] = v4.z; w[4*q+3] = v4.w;
      }
    }
    const float* xb = X + (size_t)b * (S_ * D_);
    float2 g = *reinterpret_cast<const float2*>(xb + 2 * lane);
    *reinterpret_cast<float2*>(&ring[0][2 * lane]) = g;
    g = *reinterpret_cast<const float2*>(xb + D_ + 2 * lane);
    asm volatile("" ::: "memory");

    for (int r = 0; r < S_; ++r) {
      const int cur = r & 1;
      float a0 = 0.f, a1 = 0.f, a2 = 0.f, a3 = 0.f;
      const float4* rp = reinterpret_cast<const float4*>(&ring[cur][h * 64]);
#pragma unroll
      for (int q = 0; q < 16; ++q) {
        float4 x4 = rp[q];
        a0 = fmaf(x4.x, w[4*q+0], a0);
        a1 = fmaf(x4.y, w[4*q+1], a1);
        a2 = fmaf(x4.z, w[4*q+2], a2);
        a3 = fmaf(x4.w, w[4*q+3], a3);
      }
      float p = (a0 + a1) + (a2 + a3);
      float e = p + __shfl_xor(p, 32, 64);          // r13/r14-exact emission bits
      if (r + 1 < S_) *reinterpret_cast<float2*>(&ring[cur ^ 1][2 * lane]) = g;
      if (r + 2 < S_)
        g = *reinterpret_cast<const float2*>(xb + (size_t)(r + 2) * D_ + 2 * lane);
      if (h == 0 && j < K_) e_lds[r * K_ + j] = e;
      asm volatile("" ::: "memory");                // data before counter
      if (lane == 0) *(volatile int*)&prog[0] = r + 1;
    }
    return;
  }

  if (wv == 2) {
    // ---------------- helper wave: backpointers from hist ----------------
    const int jc = (lane < K_) ? lane : (K_ - 1);
    v2f tc2[13];
#pragma unroll
    for (int q = 0; q < 13; ++q)
      tc2[q] = (v2f){Tr[(2*q) * K_ + jc], Tr[(2*q+1) * K_ + jc]};

    int seen = -1;
    for (int tp = 1; tp < S_; ++tp) {
      if (seen < tp - 1) {                          // need hist[tp-1] published
        do { seen = *(volatile int*)&prog[1]; } while (seen < tp - 1);
        asm volatile("" ::: "memory");
      }
      const float4* hp =
          reinterpret_cast<const float4*>(&hist[((tp - 1) & (WIN - 1)) * 28]);
      float4 d4[7];
#pragma unroll
      for (int q = 0; q < 7; ++q) d4[q] = hp[q];    // uniform broadcast reads
      float vs[26];
      {
        const float* df = reinterpret_cast<const float*>(d4);
        const float* tf = reinterpret_cast<const float*>(tc2);
#pragma unroll
        for (int i = 0; i < K_; ++i) vs[i] = df[i] + tf[i];   // same bits as consumer
      }
      float m[9];
#pragma unroll
      for (int i = 0; i < 8; ++i) m[i] = fmaxf(fmaxf(vs[3*i], vs[3*i+1]), vs[3*i+2]);
      m[8] = fmaxf(vs[24], vs[25]);
      float best = fmaxf(fmaxf(fmaxf(m[0], m[1]), m[2]),
                   fmaxf(fmaxf(m[3], m[4]), m[5]));
      best = fmaxf(best, fmaxf(fmaxf(m[6], m[7]), m[8]));
      int idx = 63;
#pragma unroll
      for (int i = K_ - 1; i >= 0; --i) idx = (vs[i] == best) ? i : idx;  // first-max
      if (lane < K_) bp[lane][tp] = (unsigned char)idx;
      asm volatile("" ::: "memory");                // bp before hprog
      if ((tp & 7) == 7 || tp == S_ - 1)
        if (lane == 0) *(volatile int*)&prog[2] = tp;
    }
    return;
  }

  // ---------------- consumer wave: minimal serial recurrence ----------------
  const int jc = (lane < K_) ? lane : (K_ - 1);
  v2f tc2[13];
#pragma unroll
  for (int q = 0; q < 13; ++q)
    tc2[q] = (v2f){Tr[(2*q) * K_ + jc], Tr[(2*q+1) * K_ + jc]};

  volatile int* veprog = &prog[0];
#define WAIT_E(n) do { while (*veprog < (n)) {} asm volatile("" ::: "memory"); } while (0)

  WAIT_E(2);
  float delta = e_lds[jc];                          // t = 0
  if (lane < K_) hist[lane] = delta;                // slot 0
  asm volatile("" ::: "memory");
  if (lane == 0) *(volatile int*)&prog[1] = 0;      // cprog = 0

  float4 raw[7];
  {
    const float4* p = reinterpret_cast<const float4*>(&hist[0]);
#pragma unroll
    for (int q = 0; q < 7; ++q) raw[q] = p[q];
  }
  float ev_cur = e_lds[K_ + jc];                    // e[1][jc]

  for (int ch = 0; ch < 16; ++ch) {
    const int t0 = 16 * ch, tend = t0 + 16;
    const int needE = (tend + 1 < S_) ? (tend + 1) : S_;
    WAIT_E(needE);
    if (t0 >= 32) {                                 // ring-overwrite safety
      while (*(volatile int*)&prog[2] < t0 - 16) {}
      asm volatile("" ::: "memory");
    }
    for (int t = (ch == 0 ? 1 : t0); t < tend; ++t) {
      // v = raw + tc  (13 pk_add); max tree (12 pk_max + 1)
      const v2f* rp2 = reinterpret_cast<const v2f*>(raw);
      v2f v0 = rp2[0] + tc2[0],  v1 = rp2[1] + tc2[1],  v2 = rp2[2] + tc2[2];
      v2f v3 = rp2[3] + tc2[3],  v4 = rp2[4] + tc2[4],  v5 = rp2[5] + tc2[5];
      v2f v6 = rp2[6] + tc2[6],  v7 = rp2[7] + tc2[7],  v8 = rp2[8] + tc2[8];
      v2f v9 = rp2[9] + tc2[9],  va = rp2[10] + tc2[10], vb = rp2[11] + tc2[11];
      v2f vc = rp2[12] + tc2[12];
      v2f a0 = EMAX(v0, v1), a1 = EMAX(v2, v3), a2 = EMAX(v4, v5);
      v2f a3 = EMAX(v6, v7), a4 = EMAX(v8, v9), a5 = EMAX(va, vb);
      v2f b0 = EMAX(a0, a1), b1 = EMAX(a2, a3), b2 = EMAX(a4, a5);
      v2f c0 = EMAX(b0, b1), c1 = EMAX(b2, vc);
      v2f z  = EMAX(c0, c1);
      float best = fmaxf(z.x, z.y);

      delta = best + ev_cur;                        // same op order as reference

      // publish into hist ring; fence; gather (r11-proven same-wave pattern)
      const int slot = (t & (WIN - 1)) * 28;
      if (lane < K_) hist[slot + lane] = delta;
      asm volatile("" ::: "memory");
      {
        const float4* p = reinterpret_cast<const float4*>(&hist[slot]);
#pragma unroll
        for (int q = 0; q < 7; ++q) raw[q] = p[q];
      }
      int tn = (t + 1 < S_) ? (t + 1) : (S_ - 1);
      ev_cur = e_lds[tn * K_ + jc];
      if ((t & 3) == 3)
        if (lane == 0) *(volatile int*)&prog[1] = t;  // cprog
    }
  }

  // final first-argmax over delta(255)
  int last;
  {
    const float* vf = reinterpret_cast<const float*>(raw);
    float bf = vf[0];
#pragma unroll
    for (int i = 1; i < K_; ++i) bf = fmaxf(bf, vf[i]);
    int iA = 63;
#pragma unroll
    for (int i = K_ - 1; i >= 0; --i) iA = (vf[i] == bf) ? i : iA;
    last = iA;
  }

  // wait for helper to finish all bp, then fence
  while (*(volatile int*)&prog[2] < S_ - 1) {}
  asm volatile("s_waitcnt lgkmcnt(0)" ::: "memory");

  // phase 3: backtrack (r12/r14-proven, fence-only). e_lds dead -> alias.
  unsigned char (*spec)[132] = reinterpret_cast<unsigned char (*)[132]>(e_lds);
  int* path_s = reinterpret_cast<int*>(reinterpret_cast<char*>(e_lds) + 4096);

  {
    int c = (lane < K_) ? lane : last;
    for (int k = 0; k < 128; ++k) {
      int t = (lane < K_) ? (128 - k) : (255 - k);
      bool act = (lane < K_) || (lane == 63 && k <= 126);
      if (act) {
        c = bp[c][t];
        if (lane < K_) spec[lane][t - 1] = (unsigned char)c;
        else if (t >= 129) path_s[t - 1] = c;       // covers 128..254
      }
    }
  }
  asm volatile("s_waitcnt lgkmcnt(0)" ::: "memory");

  {
    int sstar = path_s[128];
#pragma unroll
    for (int q2 = 0; q2 < 2; ++q2) {
      int t = q2 * 64 + lane;
      path_s[t] = (int)spec[sstar][t];
    }
    if (lane == 0) path_s[S_ - 1] = last;
  }
  asm volatile("s_waitcnt lgkmcnt(0)" ::: "memory");

  int* o = out + (size_t)b * S_;
#pragma unroll
  for (int q2 = 0; q2 < 4; ++q2) o[q2 * 64 + lane] = path_s[q2 * 64 + lane];
#undef WAIT_E
}

extern "C" void kernel_launch(void* const* d_in, const int* in_sizes, int n_in,
                              void* d_out, int out_size, void* d_ws, size_t ws_size,
                              hipStream_t stream) {
  (void)in_sizes; (void)n_in; (void)out_size; (void)d_ws; (void)ws_size;
  const float* X  = (const float*)d_in[0];
  const float* W  = (const float*)d_in[1];
  const float* Tr = (const float*)d_in[2];
  int* outp = (int*)d_out;
  crf_pc3<<<B_, 192, 0, stream>>>(X, W, Tr, outp);
}